// Round 6
// baseline (214.451 us; speedup 1.0000x reference)
//
#include <hip/hip_runtime.h>
#include <hip/hip_cooperative_groups.h>
#include <math.h>

namespace cg = cooperative_groups;

#define BB 2
#define SS 512
#define HH 256
#define AA 128
#define CH 4                  // chunk rows (== phase-3 row block)
#define NCH (SS / CH)         // 128 chunks per batch

// ---------------------------------------------------------------------------
// One cooperative kernel, 256 blocks x 256 threads, two grid syncs.
// Phase 1 (block = chunk c of 4 rows):
//   t[r] = sum_a q[a]*tanh(sum_h x[j0+r,h]*w_a[h,a]);  E=exp(t) (unshifted,
//   |t|<<88);  W=E*am;  C[c][h] = sum_r W[r]*x[j0+r,h].
//   x dot-product reads are wave-uniform -> scalar/broadcast path (no LDS).
// Phase 2 (wave = (b,h)): inclusive prefix-scan of C over the 128 chunks.
//   Waves 512,513: prefix-scan of E over 512 -> P.
// Phase 3 (block = rows i0..i0+3):
//   d[i,j] = (j<=i && am_i && am_j) ? E[j]/P_i : 0   (float4 stores)
//   a[i,h] = am_i/P_i * ( Cpre[i0/4-1][h] + sum_{j=i0..i} W[j]x[j,h] )
// ---------------------------------------------------------------------------
__global__ __launch_bounds__(256)
void k_all(const float* __restrict__ x,
           const int* __restrict__ am,
           const float* __restrict__ w_a,
           const float* __restrict__ query,
           float* __restrict__ Ews,     // B*S
           float* __restrict__ Cws,     // B*NCH*H, layout [b][c][h]
           float* __restrict__ Pws,     // B*S
           float* __restrict__ dout,
           float* __restrict__ aout)
{
    cg::grid_group grid = cg::this_grid();
    const int blk  = blockIdx.x;       // 0..255
    const int tid  = threadIdx.x;      // 0..255
    const int lane = tid & 63;
    const int wvi  = tid >> 6;

    __shared__ __align__(16) float sred[CH][2][AA];   // 4 KB
    __shared__ float Wl[CH];
    __shared__ __align__(16) float Ws[SS];            // 2 KB (phase 3)

    // ================= Phase 1 =================
    {
        const int b    = blk >> 7;
        const int c    = blk & 127;
        const int j0   = c * CH;
        const int a    = tid & 127;
        const int half = tid >> 7;
        // wave-uniform h-base -> x loads take the scalar/broadcast path
        const int hbase = __builtin_amdgcn_readfirstlane(half) * 128;
        const float* xr = x + (size_t)(b * SS + j0) * HH;

        float acc0 = 0.f, acc1 = 0.f, acc2 = 0.f, acc3 = 0.f;
        for (int hh = 0; hh < 128; hh += 4) {
            const int h = hbase + hh;
            const float w0 = w_a[(h + 0) * AA + a];   // coalesced, L2-hot
            const float w1 = w_a[(h + 1) * AA + a];
            const float w2 = w_a[(h + 2) * AA + a];
            const float w3 = w_a[(h + 3) * AA + a];
            const float4 x0 = *(const float4*)&xr[0 * HH + h];  // uniform
            const float4 x1 = *(const float4*)&xr[1 * HH + h];
            const float4 x2 = *(const float4*)&xr[2 * HH + h];
            const float4 x3 = *(const float4*)&xr[3 * HH + h];
            acc0 = fmaf(x0.x, w0, fmaf(x0.y, w1, fmaf(x0.z, w2, fmaf(x0.w, w3, acc0))));
            acc1 = fmaf(x1.x, w0, fmaf(x1.y, w1, fmaf(x1.z, w2, fmaf(x1.w, w3, acc1))));
            acc2 = fmaf(x2.x, w0, fmaf(x2.y, w1, fmaf(x2.z, w2, fmaf(x2.w, w3, acc2))));
            acc3 = fmaf(x3.x, w0, fmaf(x3.y, w1, fmaf(x3.z, w2, fmaf(x3.w, w3, acc3))));
        }
        sred[0][half][a] = acc0;
        sred[1][half][a] = acc1;
        sred[2][half][a] = acc2;
        sred[3][half][a] = acc3;
        __syncthreads();

        // wave wvi reduces row r=wvi; lane covers a in {lane, lane+64}
        {
            const int r = wvi;
            const float f0 = sred[r][0][lane]      + sred[r][1][lane];
            const float f1 = sred[r][0][lane + 64] + sred[r][1][lane + 64];
            float v = tanhf(f0) * query[lane] + tanhf(f1) * query[lane + 64];
            for (int off = 32; off > 0; off >>= 1)
                v += __shfl_down(v, off, 64);
            if (lane == 0) {
                const float e = expf(v);
                Wl[r] = am[b * SS + j0 + r] ? e : 0.f;
                Ews[b * SS + j0 + r] = e;
            }
        }
        __syncthreads();

        // chunk partial C[h] = sum_r W[r]*x[r][h]; thread tid = h (vector loads)
        const float cacc = fmaf(Wl[0], xr[0 * HH + tid],
                           fmaf(Wl[1], xr[1 * HH + tid],
                           fmaf(Wl[2], xr[2 * HH + tid],
                                Wl[3] * xr[3 * HH + tid])));
        Cws[(size_t)(b * NCH + c) * HH + tid] = cacc;
    }

    __threadfence();
    grid.sync();
    __threadfence();

    // ================= Phase 2 =================
    {
        const int gw = blk * 4 + wvi;              // 0..1023
        if (gw < 512) {
            // prefix-scan C over chunk dim for (b,h); lane owns c=2l,2l+1
            const int b = gw >> 8;
            const int h = gw & 255;
            float* Cb = Cws + (size_t)b * NCH * HH + h;
            const float v0 = Cb[(size_t)(2 * lane)     * HH];
            const float v1 = Cb[(size_t)(2 * lane + 1) * HH];
            float p = v0 + v1;
            for (int off = 1; off < 64; off <<= 1) {
                const float up = __shfl_up(p, off, 64);
                if (lane >= off) p += up;
            }
            Cb[(size_t)(2 * lane)     * HH] = p - v1;   // inclusive at 2l
            Cb[(size_t)(2 * lane + 1) * HH] = p;        // inclusive at 2l+1
        } else if (gw < 514) {
            // prefix-scan E -> P for batch b; lane owns 8 consecutive
            const int b = gw - 512;
            const float4 fa = *(const float4*)&Ews[b * SS + lane * 8];
            const float4 fb = *(const float4*)&Ews[b * SS + lane * 8 + 4];
            float c0 = fa.x;
            float c1 = c0 + fa.y;
            float c2 = c1 + fa.z;
            float c3 = c2 + fa.w;
            float c4 = c3 + fb.x;
            float c5 = c4 + fb.y;
            float c6 = c5 + fb.z;
            float c7 = c6 + fb.w;
            float tot = c7;
            for (int off = 1; off < 64; off <<= 1) {
                const float up = __shfl_up(tot, off, 64);
                if (lane >= off) tot += up;
            }
            const float base = tot - c7;               // exclusive offset
            float4 oa, ob;
            oa.x = base + c0; oa.y = base + c1; oa.z = base + c2; oa.w = base + c3;
            ob.x = base + c4; ob.y = base + c5; ob.z = base + c6; ob.w = base + c7;
            *(float4*)&Pws[b * SS + lane * 8]     = oa;
            *(float4*)&Pws[b * SS + lane * 8 + 4] = ob;
        }
    }

    __threadfence();
    grid.sync();
    __threadfence();

    // ================= Phase 3 =================
    {
        const int b  = blk >> 7;
        const int i0 = (blk & 127) << 2;

        const float e0 = Ews[b * SS + tid];
        const float e1 = Ews[b * SS + tid + 256];
        const int  am0 = am[b * SS + tid];
        const int  am1 = am[b * SS + tid + 256];
        Ws[tid]       = am0 ? e0 : 0.f;
        Ws[tid + 256] = am1 ? e1 : 0.f;
        __syncthreads();

        int   ami[4];
        float pinv[4];
#pragma unroll
        for (int r = 0; r < 4; ++r) {
            ami[r]  = am[b * SS + i0 + r];
            pinv[r] = 1.f / Pws[b * SS + i0 + r];
        }

        // ---- d rows: float4 stores; thread -> (row-half, col4)
        const size_t drow = (size_t)(b * SS + i0) * SS;
        const int c4 = tid & 127;
        const int jc = c4 << 2;
        const float4 wv4 = *(const float4*)&Ws[jc];
#pragma unroll
        for (int pp = 0; pp < 2; ++pp) {
            const int   r  = (tid >> 7) + 2 * pp;
            const int   i  = i0 + r;
            const float pv = pinv[r];
            const bool  on = ami[r] != 0;
            float4 o;
            o.x = (on && jc + 0 <= i) ? wv4.x * pv : 0.f;
            o.y = (on && jc + 1 <= i) ? wv4.y * pv : 0.f;
            o.z = (on && jc + 2 <= i) ? wv4.z * pv : 0.f;
            o.w = (on && jc + 3 <= i) ? wv4.w * pv : 0.f;
            *(float4*)&dout[drow + (size_t)r * SS + jc] = o;
        }

        // ---- a rows: one prefix load + 4 incremental rows
        const int nfull = i0 >> 2;
        const float* xb = x + (size_t)b * SS * HH + tid;
        const float base = nfull
            ? Cws[(size_t)(b * NCH + nfull - 1) * HH + tid] : 0.f;

        const float a0v = fmaf(Ws[i0],     xb[(size_t)(i0)     * HH], base);
        const float a1v = fmaf(Ws[i0 + 1], xb[(size_t)(i0 + 1) * HH], a0v);
        const float a2v = fmaf(Ws[i0 + 2], xb[(size_t)(i0 + 2) * HH], a1v);
        const float a3v = fmaf(Ws[i0 + 3], xb[(size_t)(i0 + 3) * HH], a2v);

        const size_t arow = (size_t)(b * SS + i0) * HH + tid;
        const float av[4] = {a0v, a1v, a2v, a3v};
#pragma unroll
        for (int r = 0; r < 4; ++r)
            aout[arow + (size_t)r * HH] = ami[r] ? av[r] * pinv[r] : 0.f;
    }
}

// ---------------------------------------------------------------------------
extern "C" void kernel_launch(void* const* d_in, const int* in_sizes, int n_in,
                              void* d_out, int out_size, void* d_ws, size_t ws_size,
                              hipStream_t stream) {
    const float* x     = (const float*)d_in[0];
    const int*   am    = (const int*)d_in[1];
    const float* w_a   = (const float*)d_in[2];
    const float* query = (const float*)d_in[3];

    float* a_out  = (float*)d_out;                   // B*S*H
    float* d_outp = a_out + (size_t)BB * SS * HH;    // B*S*S

    float* Ews = (float*)d_ws;                       // B*S floats
    float* Cws = Ews + BB * SS;                      // B*NCH*H floats (256 KB)
    float* Pws = Cws + (size_t)BB * NCH * HH;        // B*S floats

    void* args[] = { (void*)&x, (void*)&am, (void*)&w_a, (void*)&query,
                     (void*)&Ews, (void*)&Cws, (void*)&Pws,
                     (void*)&d_outp, (void*)&a_out };
    hipLaunchCooperativeKernel((const void*)k_all, dim3(BB * NCH), dim3(256),
                               args, 0, stream);
}

// Round 7
// 75.864 us; speedup vs baseline: 2.8268x; 2.8268x over previous
//
#include <hip/hip_runtime.h>
#include <math.h>

#define BB 2
#define SS 512
#define HH 256
#define AA 128
#define CH 4                  // chunk rows (== k2 row-block -> always aligned)
#define NCH (SS / CH)         // 128 chunks per batch

// ---------------------------------------------------------------------------
// Kernel 1: per 4-row chunk (256 blocks x 256 thr, full chip):
//   t[r] = sum_a q[a] * tanh( sum_h x[j0+r,h] * w_a[h,a] )
//   E[r] = exp(t[r])            (unshifted: |t| << 88 for this problem)
//   W[r] = E[r] * am[j0+r]
//   C[h] = sum_r W[r] * x[j0+r,h]
// x dot-product reads are wave-uniform (readfirstlane base) -> scalar-cache
// broadcast path, no LDS round-trip. w_a reads coalesced, L2-hot.
// ---------------------------------------------------------------------------
__global__ __launch_bounds__(256)
void k_tc(const float* __restrict__ x,
          const int* __restrict__ am,
          const float* __restrict__ w_a,
          const float* __restrict__ query,
          float* __restrict__ Ews,
          float* __restrict__ Cws) {
    const int blk  = blockIdx.x;           // 0..255
    const int b    = blk >> 7;             // 128 chunks per batch
    const int c    = blk & 127;
    const int j0   = c * CH;
    const int tid  = threadIdx.x;          // 0..255
    const int a    = tid & 127;
    const int half = tid >> 7;

    __shared__ __align__(16) float sred[CH][2][AA];   // 4 KB
    __shared__ float Wl[CH];

    // wave-uniform h-base -> x loads take the scalar/broadcast path
    const int hbase = __builtin_amdgcn_readfirstlane(half) * 128;
    const float* xr = x + (size_t)(b * SS + j0) * HH;

    float acc0 = 0.f, acc1 = 0.f, acc2 = 0.f, acc3 = 0.f;
    for (int hh = 0; hh < 128; hh += 4) {
        const int h = hbase + hh;
        const float w0 = w_a[(h + 0) * AA + a];   // coalesced, L2-hot
        const float w1 = w_a[(h + 1) * AA + a];
        const float w2 = w_a[(h + 2) * AA + a];
        const float w3 = w_a[(h + 3) * AA + a];
        const float4 x0 = *(const float4*)&xr[0 * HH + h];  // uniform addr
        const float4 x1 = *(const float4*)&xr[1 * HH + h];
        const float4 x2 = *(const float4*)&xr[2 * HH + h];
        const float4 x3 = *(const float4*)&xr[3 * HH + h];
        acc0 = fmaf(x0.x, w0, fmaf(x0.y, w1, fmaf(x0.z, w2, fmaf(x0.w, w3, acc0))));
        acc1 = fmaf(x1.x, w0, fmaf(x1.y, w1, fmaf(x1.z, w2, fmaf(x1.w, w3, acc1))));
        acc2 = fmaf(x2.x, w0, fmaf(x2.y, w1, fmaf(x2.z, w2, fmaf(x2.w, w3, acc2))));
        acc3 = fmaf(x3.x, w0, fmaf(x3.y, w1, fmaf(x3.z, w2, fmaf(x3.w, w3, acc3))));
    }
    sred[0][half][a] = acc0;
    sred[1][half][a] = acc1;
    sred[2][half][a] = acc2;
    sred[3][half][a] = acc3;
    __syncthreads();

    // wave wvi reduces row r=wvi; lane covers a in {lane, lane+64}
    const int wvi  = tid >> 6;
    const int lane = tid & 63;
    {
        const int r = wvi;
        const float f0 = sred[r][0][lane]      + sred[r][1][lane];
        const float f1 = sred[r][0][lane + 64] + sred[r][1][lane + 64];
        float v = tanhf(f0) * query[lane] + tanhf(f1) * query[lane + 64];
        for (int off = 32; off > 0; off >>= 1)
            v += __shfl_down(v, off, 64);
        if (lane == 0) {
            const float e = expf(v);
            Wl[r] = am[b * SS + j0 + r] ? e : 0.f;
            Ews[b * SS + j0 + r] = e;
        }
    }
    __syncthreads();

    // chunk partial C[h] = sum_r W[r]*x[r][h]; thread tid = h (L2-hot reads)
    const float cacc = fmaf(Wl[0], xr[0 * HH + tid],
                       fmaf(Wl[1], xr[1 * HH + tid],
                       fmaf(Wl[2], xr[2 * HH + tid],
                            Wl[3] * xr[3 * HH + tid])));
    Cws[(size_t)(b * NCH + c) * HH + tid] = cacc;
}

// ---------------------------------------------------------------------------
// Kernel 2 (256 blocks x 256 thr; 4 output rows i0..i0+3, chunk-aligned):
//   P_i = sum_{j<=i} E[j]
//   d[i,j] = (j<=i && am_i && am_j) ? E[j]/P_i : 0      (float4 stores)
//   a[i,h] = am_i/P_i * ( sum_{cc < i0/4} C[cc][h] + incremental rows )
// Chunk loop uses 8 accumulators to keep 8 L2 loads in flight (straggler
// block has 127 chunk loads; 8-deep ILP -> ~16 latency rounds).
// ---------------------------------------------------------------------------
__global__ __launch_bounds__(256)
void k_out(const float* __restrict__ Ews,
           const float* __restrict__ Cws,
           const int* __restrict__ am,
           const float* __restrict__ x,
           float* __restrict__ dout,
           float* __restrict__ aout) {
    const int blk  = blockIdx.x;           // 0..255
    const int b    = blk >> 7;
    const int i0   = (blk & 127) << 2;
    const int tid  = threadIdx.x;          // 0..255
    const int lane = tid & 63;
    const int wvi  = tid >> 6;

    __shared__ float Es[SS];
    __shared__ __align__(16) float Ws[SS];
    __shared__ float red[4];
    __shared__ float Pinv[4];

    const float e0 = Ews[b * SS + tid];
    const float e1 = Ews[b * SS + tid + 256];
    const int  am0 = am[b * SS + tid];
    const int  am1 = am[b * SS + tid + 256];
    Es[tid] = e0;             Es[tid + 256] = e1;
    Ws[tid] = am0 ? e0 : 0.f; Ws[tid + 256] = am1 ? e1 : 0.f;

    // P_base = sum_{j<=i0} E[j]
    float p = ((tid <= i0) ? e0 : 0.f) + ((tid + 256 <= i0) ? e1 : 0.f);
    for (int off = 32; off > 0; off >>= 1)
        p += __shfl_down(p, off, 64);
    if (lane == 0) red[wvi] = p;
    __syncthreads();
    if (tid == 0) {
        const float P0 = red[0] + red[1] + red[2] + red[3];
        const float P1 = P0 + Es[i0 + 1];
        const float P2 = P1 + Es[i0 + 2];
        const float P3 = P2 + Es[i0 + 3];
        Pinv[0] = 1.f / P0; Pinv[1] = 1.f / P1;
        Pinv[2] = 1.f / P2; Pinv[3] = 1.f / P3;
    }
    __syncthreads();

    const int* amg = am + b * SS;
    int ami[4];
#pragma unroll
    for (int r = 0; r < 4; ++r) ami[r] = amg[i0 + r];

    // ---- d rows: float4 stores; thread -> (row-half, col4)
    const size_t drow = (size_t)(b * SS + i0) * SS;
    const int c4 = tid & 127;
    const int jc = c4 << 2;
    const float4 wv4 = *(const float4*)&Ws[jc];
#pragma unroll
    for (int pp = 0; pp < 2; ++pp) {
        const int   r  = (tid >> 7) + 2 * pp;
        const int   i  = i0 + r;
        const float pv = Pinv[r];
        const bool  on = ami[r] != 0;
        float4 o;
        o.x = (on && jc + 0 <= i) ? wv4.x * pv : 0.f;
        o.y = (on && jc + 1 <= i) ? wv4.y * pv : 0.f;
        o.z = (on && jc + 2 <= i) ? wv4.z * pv : 0.f;
        o.w = (on && jc + 3 <= i) ? wv4.w * pv : 0.f;
        *(float4*)&dout[drow + (size_t)r * SS + jc] = o;
    }

    // ---- a rows: chunk-aligned prefix via C (8-way ILP), then 4 raw rows
    const int nfull = i0 >> 2;             // chunks strictly below i0
    const float* xb = x + (size_t)b * SS * HH + tid;
    const float* Cb = Cws + (size_t)b * NCH * HH + tid;

    float s0 = 0.f, s1 = 0.f, s2 = 0.f, s3 = 0.f;
    float s4 = 0.f, s5 = 0.f, s6 = 0.f, s7 = 0.f;
    int cc = 0;
    for (; cc + 8 <= nfull; cc += 8) {
        s0 += Cb[(size_t)(cc + 0) * HH];
        s1 += Cb[(size_t)(cc + 1) * HH];
        s2 += Cb[(size_t)(cc + 2) * HH];
        s3 += Cb[(size_t)(cc + 3) * HH];
        s4 += Cb[(size_t)(cc + 4) * HH];
        s5 += Cb[(size_t)(cc + 5) * HH];
        s6 += Cb[(size_t)(cc + 6) * HH];
        s7 += Cb[(size_t)(cc + 7) * HH];
    }
    for (; cc < nfull; ++cc)
        s0 += Cb[(size_t)cc * HH];
    const float base = ((s0 + s1) + (s2 + s3)) + ((s4 + s5) + (s6 + s7));

    const float a0v = fmaf(Ws[i0],     xb[(size_t)(i0)     * HH], base);
    const float a1v = fmaf(Ws[i0 + 1], xb[(size_t)(i0 + 1) * HH], a0v);
    const float a2v = fmaf(Ws[i0 + 2], xb[(size_t)(i0 + 2) * HH], a1v);
    const float a3v = fmaf(Ws[i0 + 3], xb[(size_t)(i0 + 3) * HH], a2v);

    const size_t arow = (size_t)(b * SS + i0) * HH + tid;
    const float av[4] = {a0v, a1v, a2v, a3v};
#pragma unroll
    for (int r = 0; r < 4; ++r)
        aout[arow + (size_t)r * HH] = ami[r] ? av[r] * Pinv[r] : 0.f;
}

// ---------------------------------------------------------------------------
extern "C" void kernel_launch(void* const* d_in, const int* in_sizes, int n_in,
                              void* d_out, int out_size, void* d_ws, size_t ws_size,
                              hipStream_t stream) {
    const float* x     = (const float*)d_in[0];
    const int*   am    = (const int*)d_in[1];
    const float* w_a   = (const float*)d_in[2];
    const float* query = (const float*)d_in[3];

    float* a_out  = (float*)d_out;                   // B*S*H
    float* d_outp = a_out + (size_t)BB * SS * HH;    // B*S*S

    float* Ews = (float*)d_ws;                       // B*S floats
    float* Cws = Ews + BB * SS;                      // B*NCH*H floats (256 KB)

    k_tc <<<BB * NCH,    256, 0, stream>>>(x, am, w_a, query, Ews, Cws);
    k_out<<<BB * SS / 4, 256, 0, stream>>>(Ews, Cws, am, x, d_outp, a_out);
}